// Round 3
// baseline (2787.724 us; speedup 1.0000x reference)
//
#include <hip/hip_runtime.h>

#define N_NODES 50000
#define N_EDGES 800000
#define BN_EPS 1e-5f

// ---------------------------------------------------------------------------
__global__ void zero_f(float* __restrict__ p, int n) {
    int i = blockIdx.x * blockDim.x + threadIdx.x;
    int stride = gridDim.x * blockDim.x;
    for (; i < n; i += stride) p[i] = 0.f;
}
__global__ void zero_i(int* __restrict__ p, int n) {
    int i = blockIdx.x * blockDim.x + threadIdx.x;
    int stride = gridDim.x * blockDim.x;
    for (; i < n; i += stride) p[i] = 0;
}

// ---------------------------------------------------------------------------
// CSR build
__global__ void hist_kernel(const int* __restrict__ dst, int* __restrict__ cnt) {
    int i = blockIdx.x * blockDim.x + threadIdx.x;
    int stride = gridDim.x * blockDim.x;
    for (; i < N_EDGES; i += stride) atomicAdd(&cnt[dst[i]], 1);
}
__global__ void scan1_kernel(const int* __restrict__ cnt, int* __restrict__ rp,
                             int* __restrict__ bsum) {
    __shared__ int s[256];
    int t = threadIdx.x;
    int idx = blockIdx.x * 256 + t;
    int v = (idx < N_NODES) ? cnt[idx] : 0;
    s[t] = v;
    __syncthreads();
    for (int off = 1; off < 256; off <<= 1) {
        int x = 0;
        if (t >= off) x = s[t - off];
        __syncthreads();
        s[t] += x;
        __syncthreads();
    }
    if (idx < N_NODES) rp[idx] = s[t] - v;
    if (t == 255) bsum[blockIdx.x] = s[255];
}
__global__ void scan2_kernel(int* __restrict__ bsum, int nb) {
    __shared__ int s[256];
    int t = threadIdx.x;
    int v = (t < nb) ? bsum[t] : 0;
    s[t] = v;
    __syncthreads();
    for (int off = 1; off < 256; off <<= 1) {
        int x = 0;
        if (t >= off) x = s[t - off];
        __syncthreads();
        s[t] += x;
        __syncthreads();
    }
    if (t < nb) bsum[t] = s[t] - v;
}
__global__ void scan3_kernel(int* __restrict__ rp, const int* __restrict__ bsum) {
    int idx = blockIdx.x * 256 + threadIdx.x;
    if (idx < N_NODES) rp[idx] += bsum[blockIdx.x];
    if (idx == 0) rp[N_NODES] = N_EDGES;
}
__global__ void fill_kernel(const int* __restrict__ src, const int* __restrict__ dst,
                            const int* __restrict__ rp, int* __restrict__ cur,
                            int* __restrict__ ssrc) {
    int i = blockIdx.x * blockDim.x + threadIdx.x;
    int stride = gridDim.x * blockDim.x;
    for (; i < N_EDGES; i += stride) {
        int d = dst[i];
        int p = rp[d] + atomicAdd(&cur[d], 1);
        ssrc[p] = src[i];
    }
}

// ---------------------------------------------------------------------------
// embedding Linear(5,32)+ReLU with fused BN stats
__global__ __launch_bounds__(256) void emb_fused(
    const float* __restrict__ x, const float* __restrict__ W,
    const float* __restrict__ b, float* __restrict__ out,
    float* __restrict__ stats) {
    __shared__ float lsum[32], lssq[32];
    if (threadIdx.x < 32) { lsum[threadIdx.x] = 0.f; lssq[threadIdx.x] = 0.f; }
    __syncthreads();
    const int o = threadIdx.x & 31;  // invariant across grid-stride iterations
    const int total = N_NODES * 32;
    float mys = 0.f, myq = 0.f;
    for (int base = blockIdx.x * 256; base < total; base += gridDim.x * 256) {
        int idx = base + threadIdx.x;
        float acc = 0.f;
        if (idx < total) {
            int n = idx >> 5;
            const float* xr = x + n * 5;
            acc = b[o];
#pragma unroll
            for (int k = 0; k < 5; ++k) acc += xr[k] * W[k * 32 + o];
            acc = fmaxf(acc, 0.f);
            out[idx] = acc;
        }
        mys += acc;
        myq += acc * acc;
    }
    mys += __shfl_xor(mys, 32);
    myq += __shfl_xor(myq, 32);
    if ((threadIdx.x & 63) < 32) { atomicAdd(&lsum[o], mys); atomicAdd(&lssq[o], myq); }
    __syncthreads();
    if (threadIdx.x < 32) {
        atomicAdd(&stats[threadIdx.x], lsum[threadIdx.x]);
        atomicAdd(&stats[32 + threadIdx.x], lssq[threadIdx.x]);
    }
}

// ---------------------------------------------------------------------------
// out[n][o0+j] = brel + agg@Wrel + h@Wroot, register-blocked, fused BN stats.
template <int DIN, int DOUT>
__global__ __launch_bounds__(256) void gconv_fused(
    const float* __restrict__ h, const float* __restrict__ agg,
    const float* __restrict__ Wrel, const float* __restrict__ brel,
    const float* __restrict__ Wroot, float* __restrict__ out,
    float* __restrict__ stats) {
    constexpr int OB = 32;
    __shared__ float lsum[OB], lssq[OB];
    const int tid = threadIdx.x;
    if (tid < OB) { lsum[tid] = 0.f; lssq[tid] = 0.f; }
    __syncthreads();

    const int n = blockIdx.x * 256 + tid;
    const bool alive = n < N_NODES;
    const int nn = alive ? n : (N_NODES - 1);
    const int o0 = blockIdx.y * OB;

    float acc[OB];
#pragma unroll
    for (int j = 0; j < OB; ++j) acc[j] = brel[o0 + j];

    const float4* hr = (const float4*)(h + (size_t)nn * DIN);
    const float4* ar = (const float4*)(agg + (size_t)nn * DIN);
#pragma unroll
    for (int k4 = 0; k4 < DIN / 4; ++k4) {
        float4 hv4 = hr[k4];
        float4 av4 = ar[k4];
        const float* hv = (const float*)&hv4;
        const float* av = (const float*)&av4;
#pragma unroll
        for (int u = 0; u < 4; ++u) {
            const int k = 4 * k4 + u;
            const float* wr = Wrel + k * DOUT + o0;   // uniform address -> scalar loads
            const float* wo = Wroot + k * DOUT + o0;
            const float a = av[u];
            const float hh = hv[u];
#pragma unroll
            for (int j = 0; j < OB; ++j) acc[j] += a * wr[j] + hh * wo[j];
        }
    }

    if (alive) {
        float4* orow = (float4*)(out + (size_t)n * DOUT + o0);
#pragma unroll
        for (int j4 = 0; j4 < OB / 4; ++j4) {
            float4 v;
            v.x = acc[4 * j4]; v.y = acc[4 * j4 + 1];
            v.z = acc[4 * j4 + 2]; v.w = acc[4 * j4 + 3];
            orow[j4] = v;
        }
    } else {
#pragma unroll
        for (int j = 0; j < OB; ++j) acc[j] = 0.f;
    }

    const int lane = tid & 63;
#pragma unroll
    for (int j = 0; j < OB; ++j) {
        float s = acc[j], q = acc[j] * acc[j];
#pragma unroll
        for (int d = 1; d < 64; d <<= 1) {
            s += __shfl_xor(s, d);
            q += __shfl_xor(q, d);
        }
        if (lane == 0) { atomicAdd(&lsum[j], s); atomicAdd(&lssq[j], q); }
    }
    __syncthreads();
    if (tid < OB) {
        atomicAdd(&stats[o0 + tid], lsum[tid]);
        atomicAdd(&stats[DOUT + o0 + tid], lssq[tid]);
    }
}

// ---------------------------------------------------------------------------
// P = h@Wrel ; Q = h@Wroot + brel  (register-blocked dual matmul, no stats)
template <int DIN, int DOUT>
__global__ __launch_bounds__(256) void prem2_kernel(
    const float* __restrict__ h, const float* __restrict__ Wrel,
    const float* __restrict__ brel, const float* __restrict__ Wroot,
    float* __restrict__ P, float* __restrict__ Q) {
    constexpr int OB = 32;
    const int n = blockIdx.x * 256 + threadIdx.x;
    if (n >= N_NODES) return;
    const int o0 = blockIdx.y * OB;

    float accp[OB], accq[OB];
#pragma unroll
    for (int j = 0; j < OB; ++j) { accp[j] = 0.f; accq[j] = brel[o0 + j]; }

    const float4* hr = (const float4*)(h + (size_t)n * DIN);
#pragma unroll
    for (int k4 = 0; k4 < DIN / 4; ++k4) {
        float4 hv4 = hr[k4];
        const float* hv = (const float*)&hv4;
#pragma unroll
        for (int u = 0; u < 4; ++u) {
            const int k = 4 * k4 + u;
            const float* wr = Wrel + k * DOUT + o0;
            const float* wo = Wroot + k * DOUT + o0;
            const float hh = hv[u];
#pragma unroll
            for (int j = 0; j < OB; ++j) {
                accp[j] += hh * wr[j];
                accq[j] += hh * wo[j];
            }
        }
    }
    float4* prow = (float4*)(P + (size_t)n * DOUT + o0);
    float4* qrow = (float4*)(Q + (size_t)n * DOUT + o0);
#pragma unroll
    for (int j4 = 0; j4 < OB / 4; ++j4) {
        float4 vp, vq;
        vp.x = accp[4 * j4]; vp.y = accp[4 * j4 + 1]; vp.z = accp[4 * j4 + 2]; vp.w = accp[4 * j4 + 3];
        vq.x = accq[4 * j4]; vq.y = accq[4 * j4 + 1]; vq.z = accq[4 * j4 + 2]; vq.w = accq[4 * j4 + 3];
        prow[j4] = vp;
        qrow[j4] = vq;
    }
}

// ---------------------------------------------------------------------------
// agg[n][4q..4q+3] = sum over CSR row of h[ssrc[e]][4q..4q+3]
template <int LOGD>
__global__ __launch_bounds__(256) void gather_agg(
    const float* __restrict__ h, const int* __restrict__ rp,
    const int* __restrict__ ssrc, float4* __restrict__ agg) {
    constexpr int QSH = LOGD - 2;
    int tid = blockIdx.x * 256 + threadIdx.x;
    int node = tid >> QSH;
    if (node >= N_NODES) return;
    int q = tid & ((1 << QSH) - 1);
    int e0 = rp[node], e1 = rp[node + 1];
    float4 acc = make_float4(0.f, 0.f, 0.f, 0.f);
    for (int e = e0; e < e1; ++e) {
        const float4* row = (const float4*)(h + ((size_t)ssrc[e] << LOGD));
        float4 v = row[q];
        acc.x += v.x; acc.y += v.y; acc.z += v.z; acc.w += v.w;
    }
    agg[tid] = acc;
}

// ---------------------------------------------------------------------------
// out[n][f] = Q_preloaded + sum over CSR row of P[ssrc[e]][f]; fused BN stats.
template <int LOGD>
__global__ __launch_bounds__(256) void gather_add_fused(
    const float* __restrict__ P, const int* __restrict__ rp,
    const int* __restrict__ ssrc, float4* __restrict__ out,
    float* __restrict__ stats) {
    constexpr int D = 1 << LOGD;
    constexpr int Q4 = D / 4;  // lanes per node
    __shared__ float lsum[D], lssq[D];
    if (threadIdx.x < D) { lsum[threadIdx.x] = 0.f; lssq[threadIdx.x] = 0.f; }
    __syncthreads();

    const int total = N_NODES * Q4;
    const int q = threadIdx.x & (Q4 - 1);  // invariant across iterations
    float4 mys = make_float4(0.f, 0.f, 0.f, 0.f);
    float4 myq = make_float4(0.f, 0.f, 0.f, 0.f);

    for (int base = blockIdx.x * 256; base < total; base += gridDim.x * 256) {
        int tid = base + threadIdx.x;
        float4 acc = make_float4(0.f, 0.f, 0.f, 0.f);
        if (tid < total) {
            int node = tid >> (LOGD - 2);
            int e0 = rp[node], e1 = rp[node + 1];
            acc = out[tid];  // Q preloaded
            for (int e = e0; e < e1; ++e) {
                const float4* row = (const float4*)(P + ((size_t)ssrc[e] << LOGD));
                float4 v = row[q];
                acc.x += v.x; acc.y += v.y; acc.z += v.z; acc.w += v.w;
            }
            out[tid] = acc;
        }
        mys.x += acc.x; mys.y += acc.y; mys.z += acc.z; mys.w += acc.w;
        myq.x += acc.x * acc.x; myq.y += acc.y * acc.y;
        myq.z += acc.z * acc.z; myq.w += acc.w * acc.w;
    }
    // reduce across the node-groups within the wave (lanes with same q)
#pragma unroll
    for (int d = Q4; d < 64; d <<= 1) {
        mys.x += __shfl_xor(mys.x, d); mys.y += __shfl_xor(mys.y, d);
        mys.z += __shfl_xor(mys.z, d); mys.w += __shfl_xor(mys.w, d);
        myq.x += __shfl_xor(myq.x, d); myq.y += __shfl_xor(myq.y, d);
        myq.z += __shfl_xor(myq.z, d); myq.w += __shfl_xor(myq.w, d);
    }
    if ((threadIdx.x & 63) < Q4) {
        atomicAdd(&lsum[4 * q + 0], mys.x); atomicAdd(&lsum[4 * q + 1], mys.y);
        atomicAdd(&lsum[4 * q + 2], mys.z); atomicAdd(&lsum[4 * q + 3], mys.w);
        atomicAdd(&lssq[4 * q + 0], myq.x); atomicAdd(&lssq[4 * q + 1], myq.y);
        atomicAdd(&lssq[4 * q + 2], myq.z); atomicAdd(&lssq[4 * q + 3], myq.w);
    }
    __syncthreads();
    if (threadIdx.x < D) {
        atomicAdd(&stats[threadIdx.x], lsum[threadIdx.x]);
        atomicAdd(&stats[D + threadIdx.x], lssq[threadIdx.x]);
    }
}

// ---------------------------------------------------------------------------
// in-place batchnorm (+ optional relu), float4
__global__ __launch_bounds__(256) void bn_kernel(
    float4* __restrict__ h, const float* __restrict__ g,
    const float* __restrict__ beta, const float* __restrict__ stats,
    int logD, int relu) {
    const int D = 1 << logD;
    const int total4 = N_NODES << (logD - 2);
    const float invN = 1.f / (float)N_NODES;
    int idx = blockIdx.x * blockDim.x + threadIdx.x;
    int stride = gridDim.x * blockDim.x;
    for (; idx < total4; idx += stride) {
        int f = (idx & ((D >> 2) - 1)) << 2;
        float4 v = h[idx];
        float* vp = (float*)&v;
#pragma unroll
        for (int c = 0; c < 4; ++c) {
            float m = stats[f + c] * invN;
            float var = stats[D + f + c] * invN - m * m;
            float y = (vp[c] - m) * rsqrtf(var + BN_EPS) * g[f + c] + beta[f + c];
            if (relu) y = fmaxf(y, 0.f);
            vp[c] = y;
        }
        h[idx] = v;
    }
}

// ---------------------------------------------------------------------------
// fused: BN(layer3)+ReLU -> Linear(32,16)+ReLU -> Linear(16,2)
__global__ __launch_bounds__(256) void outmlp_kernel(
    const float* __restrict__ h, const float* __restrict__ stats,
    const float* __restrict__ g, const float* __restrict__ beta,
    const float* __restrict__ W1, const float* __restrict__ b1,
    const float* __restrict__ W2, const float* __restrict__ b2,
    float* __restrict__ out) {
    int n = blockIdx.x * 256 + threadIdx.x;
    if (n >= N_NODES) return;
    const float invN = 1.f / (float)N_NODES;
    const float4* hr4 = (const float4*)(h + (size_t)n * 32);
    float hv[32];
#pragma unroll
    for (int k4 = 0; k4 < 8; ++k4) {
        float4 v = hr4[k4];
        float* vp = (float*)&v;
#pragma unroll
        for (int c = 0; c < 4; ++c) {
            int f = 4 * k4 + c;
            float m = stats[f] * invN;
            float var = stats[32 + f] * invN - m * m;
            hv[f] = fmaxf((vp[c] - m) * rsqrtf(var + BN_EPS) * g[f] + beta[f], 0.f);
        }
    }
    float hid[16];
#pragma unroll
    for (int j = 0; j < 16; ++j) hid[j] = b1[j];
#pragma unroll
    for (int k = 0; k < 32; ++k) {
        float hk = hv[k];
#pragma unroll
        for (int j = 0; j < 16; ++j) hid[j] += hk * W1[k * 16 + j];
    }
    float o0 = b2[0], o1 = b2[1];
#pragma unroll
    for (int j = 0; j < 16; ++j) {
        float t = fmaxf(hid[j], 0.f);
        o0 += t * W2[j * 2 + 0];
        o1 += t * W2[j * 2 + 1];
    }
    out[n * 2 + 0] = o0;
    out[n * 2 + 1] = o1;
}

// ---------------------------------------------------------------------------
extern "C" void kernel_launch(void* const* d_in, const int* in_sizes, int n_in,
                              void* d_out, int out_size, void* d_ws, size_t ws_size,
                              hipStream_t stream) {
    const float* x        = (const float*)d_in[0];
    const int*   ei       = (const int*)d_in[1];
    const int*   src      = ei;
    const int*   dst      = ei + N_EDGES;
    const float* emb_W    = (const float*)d_in[2];
    const float* emb_b    = (const float*)d_in[3];
    const float* emb_g    = (const float*)d_in[4];
    const float* emb_beta = (const float*)d_in[5];
    const float* out_W1   = (const float*)d_in[26];
    const float* out_b1   = (const float*)d_in[27];
    const float* out_W2   = (const float*)d_in[28];
    const float* out_b2   = (const float*)d_in[29];

    float* ws = (float*)d_ws;
    const size_t HMAX = (size_t)N_NODES * 128;
    float* hA    = ws;
    float* hB    = ws + HMAX;
    float* P     = ws + 2 * HMAX;                        // N x 64 max
    float* stats = ws + 2 * HMAX + (size_t)N_NODES * 64; // 5 x 256
    int*   rp    = (int*)(stats + 5 * 256);
    int*   cnt   = rp + N_NODES + 1;
    int*   bsum  = cnt + N_NODES;
    int*   ssrc  = bsum + 256;

    float* st0 = stats;        // emb BN (D=32)
    float* st1 = stats + 256;  // L0 (D=64)
    float* st2 = stats + 512;  // L1 (D=128)
    float* st3 = stats + 768;  // L2 (D=64)
    float* st4 = stats + 1024; // L3 (D=32)

    const int BS = 256;
    const int NB = (N_NODES + BS - 1) / BS;  // 196

    // ---- zero all stats once ----
    zero_f<<<2, BS, 0, stream>>>(stats, 5 * 256);

    // ---- CSR build ----
    zero_i<<<64, BS, 0, stream>>>(cnt, N_NODES);
    hist_kernel<<<1024, BS, 0, stream>>>(dst, cnt);
    scan1_kernel<<<NB, 256, 0, stream>>>(cnt, rp, bsum);
    scan2_kernel<<<1, 256, 0, stream>>>(bsum, NB);
    scan3_kernel<<<NB, 256, 0, stream>>>(rp, bsum);
    zero_i<<<64, BS, 0, stream>>>(cnt, N_NODES);
    fill_kernel<<<1024, BS, 0, stream>>>(src, dst, rp, cnt, ssrc);

    // ---- embedding + BN ----
    emb_fused<<<512, BS, 0, stream>>>(x, emb_W, emb_b, hA, st0);
    bn_kernel<<<1563, BS, 0, stream>>>((float4*)hA, emb_g, emb_beta, st0, 5, 0);

    // ---- layer 0: 32 -> 64, gather input side ----
    gather_agg<5><<<(N_NODES * 8 + BS - 1) / BS, BS, 0, stream>>>(hA, rp, ssrc, (float4*)P);
    gconv_fused<32, 64><<<dim3(NB, 2), BS, 0, stream>>>(
        hA, P, (const float*)d_in[6], (const float*)d_in[7], (const float*)d_in[8], hB, st1);
    bn_kernel<<<2048, BS, 0, stream>>>((float4*)hB, (const float*)d_in[9], (const float*)d_in[10], st1, 6, 1);

    // ---- layer 1: 64 -> 128, gather input side ----
    gather_agg<6><<<(N_NODES * 16 + BS - 1) / BS, BS, 0, stream>>>(hB, rp, ssrc, (float4*)P);
    gconv_fused<64, 128><<<dim3(NB, 4), BS, 0, stream>>>(
        hB, P, (const float*)d_in[11], (const float*)d_in[12], (const float*)d_in[13], hA, st2);
    bn_kernel<<<2048, BS, 0, stream>>>((float4*)hA, (const float*)d_in[14], (const float*)d_in[15], st2, 7, 1);

    // ---- layer 2: 128 -> 64, pre-multiply then gather ----
    prem2_kernel<128, 64><<<dim3(NB, 2), BS, 0, stream>>>(
        hA, (const float*)d_in[16], (const float*)d_in[17], (const float*)d_in[18], P, hB);
    gather_add_fused<6><<<512, BS, 0, stream>>>(P, rp, ssrc, (float4*)hB, st3);
    bn_kernel<<<2048, BS, 0, stream>>>((float4*)hB, (const float*)d_in[19], (const float*)d_in[20], st3, 6, 1);

    // ---- layer 3: 64 -> 32, pre-multiply then gather ----
    prem2_kernel<64, 32><<<dim3(NB, 1), BS, 0, stream>>>(
        hB, (const float*)d_in[21], (const float*)d_in[22], (const float*)d_in[23], P, hA);
    gather_add_fused<5><<<512, BS, 0, stream>>>(P, rp, ssrc, (float4*)hA, st4);

    // ---- fused BN(L3)+ReLU + output MLP ----
    outmlp_kernel<<<NB, BS, 0, stream>>>(
        hA, st4, (const float*)d_in[24], (const float*)d_in[25],
        out_W1, out_b1, out_W2, out_b2, (float*)d_out);
}

// Round 4
// 2749.457 us; speedup vs baseline: 1.0139x; 1.0139x over previous
//
#include <hip/hip_runtime.h>

#define N_NODES 50000
#define N_EDGES 800000
#define BN_EPS 1e-5f

__device__ __forceinline__ void fma4(float4& a, float s, const float4& w) {
    a.x += s * w.x; a.y += s * w.y; a.z += s * w.z; a.w += s * w.w;
}

// ---------------------------------------------------------------------------
__global__ void zero_f(float* __restrict__ p, int n) {
    int i = blockIdx.x * blockDim.x + threadIdx.x;
    int stride = gridDim.x * blockDim.x;
    for (; i < n; i += stride) p[i] = 0.f;
}
__global__ void zero_i(int* __restrict__ p, int n) {
    int i = blockIdx.x * blockDim.x + threadIdx.x;
    int stride = gridDim.x * blockDim.x;
    for (; i < n; i += stride) p[i] = 0;
}

// ---------------------------------------------------------------------------
// CSR build
__global__ void hist_kernel(const int* __restrict__ dst, int* __restrict__ cnt) {
    int i = blockIdx.x * blockDim.x + threadIdx.x;
    int stride = gridDim.x * blockDim.x;
    for (; i < N_EDGES; i += stride) atomicAdd(&cnt[dst[i]], 1);
}
__global__ void scan1_kernel(const int* __restrict__ cnt, int* __restrict__ rp,
                             int* __restrict__ bsum) {
    __shared__ int s[256];
    int t = threadIdx.x;
    int idx = blockIdx.x * 256 + t;
    int v = (idx < N_NODES) ? cnt[idx] : 0;
    s[t] = v;
    __syncthreads();
    for (int off = 1; off < 256; off <<= 1) {
        int x = 0;
        if (t >= off) x = s[t - off];
        __syncthreads();
        s[t] += x;
        __syncthreads();
    }
    if (idx < N_NODES) rp[idx] = s[t] - v;
    if (t == 255) bsum[blockIdx.x] = s[255];
}
__global__ void scan2_kernel(int* __restrict__ bsum, int nb) {
    __shared__ int s[256];
    int t = threadIdx.x;
    int v = (t < nb) ? bsum[t] : 0;
    s[t] = v;
    __syncthreads();
    for (int off = 1; off < 256; off <<= 1) {
        int x = 0;
        if (t >= off) x = s[t - off];
        __syncthreads();
        s[t] += x;
        __syncthreads();
    }
    if (t < nb) bsum[t] = s[t] - v;
}
__global__ void scan3_kernel(int* __restrict__ rp, const int* __restrict__ bsum) {
    int idx = blockIdx.x * 256 + threadIdx.x;
    if (idx < N_NODES) rp[idx] += bsum[blockIdx.x];
    if (idx == 0) rp[N_NODES] = N_EDGES;
}
__global__ void fill_kernel(const int* __restrict__ src, const int* __restrict__ dst,
                            const int* __restrict__ rp, int* __restrict__ cur,
                            int* __restrict__ ssrc) {
    int i = blockIdx.x * blockDim.x + threadIdx.x;
    int stride = gridDim.x * blockDim.x;
    for (; i < N_EDGES; i += stride) {
        int d = dst[i];
        int p = rp[d] + atomicAdd(&cur[d], 1);
        ssrc[p] = src[i];
    }
}

// ---------------------------------------------------------------------------
// embedding Linear(5,32)+ReLU  (weight loads coalesced across lanes)
__global__ void emb_kernel(const float* __restrict__ x, const float* __restrict__ W,
                           const float* __restrict__ b, float* __restrict__ out) {
    int idx = blockIdx.x * blockDim.x + threadIdx.x;
    if (idx >= N_NODES * 32) return;
    int n = idx >> 5;
    int o = idx & 31;
    const float* xr = x + n * 5;
    float acc = b[o];
#pragma unroll
    for (int k = 0; k < 5; ++k) acc += xr[k] * W[k * 32 + o];
    out[idx] = fmaxf(acc, 0.f);
}

// ---------------------------------------------------------------------------
// per-feature sum & sumsq (stats must be pre-zeroed)
__global__ void stats_kernel(const float* __restrict__ h, float* __restrict__ stats, int D) {
    extern __shared__ float lds[];  // 2*D floats
    int tid = threadIdx.x;
    for (int i = tid; i < 2 * D; i += blockDim.x) lds[i] = 0.f;
    __syncthreads();
    int gtid = blockIdx.x * blockDim.x + tid;
    int f = gtid & (D - 1);
    int row = gtid / D;
    int rstride = (gridDim.x * blockDim.x) / D;
    float s = 0.f, ss = 0.f;
    for (; row < N_NODES; row += rstride) {
        float v = h[row * D + f];
        s += v;
        ss += v * v;
    }
    atomicAdd(&lds[f], s);
    atomicAdd(&lds[D + f], ss);
    __syncthreads();
    for (int i = tid; i < 2 * D; i += blockDim.x) atomicAdd(&stats[i], lds[i]);
}

// in-place batchnorm (+ optional relu), float4
__global__ __launch_bounds__(256) void bn_kernel(
    float4* __restrict__ h, const float* __restrict__ g,
    const float* __restrict__ beta, const float* __restrict__ stats,
    int logD, int relu) {
    const int D = 1 << logD;
    const int total4 = N_NODES << (logD - 2);
    const float invN = 1.f / (float)N_NODES;
    int idx = blockIdx.x * blockDim.x + threadIdx.x;
    int stride = gridDim.x * blockDim.x;
    for (; idx < total4; idx += stride) {
        int f = (idx & ((D >> 2) - 1)) << 2;
        float4 v = h[idx];
        float* vp = (float*)&v;
#pragma unroll
        for (int c = 0; c < 4; ++c) {
            float m = stats[f + c] * invN;
            float var = stats[D + f + c] * invN - m * m;
            float y = (vp[c] - m) * rsqrtf(var + BN_EPS) * g[f + c] + beta[f + c];
            if (relu) y = fmaxf(y, 0.f);
            vp[c] = y;
        }
        h[idx] = v;
    }
}

// ---------------------------------------------------------------------------
// dual matmul: out[n][o] = brel[o] + agg[n]@Wrel[:,o] + h[n]@Wroot[:,o]
// Thread owns 4 output cols (per-lane varying -> coalesced weight loads)
// x NPT nodes (amortizes weight loads).
template <int DIN, int DOUT>
__global__ __launch_bounds__(256) void gconv_v2(
    const float* __restrict__ h, const float* __restrict__ agg,
    const float* __restrict__ Wrel, const float* __restrict__ brel,
    const float* __restrict__ Wroot, float* __restrict__ out) {
    constexpr int OBL = (DOUT >= 64) ? 64 : 32;  // outputs per y-block
    constexpr int LPN = OBL / 4;                 // lanes per node (16 or 8)
    constexpr int SLOTS = 256 / LPN;             // node slots per block
    constexpr int NPT = 4;                       // nodes per thread
    const int q = threadIdx.x & (LPN - 1);
    const int slot = threadIdx.x / LPN;
    const int o0 = blockIdx.y * OBL + q * 4;

    float4 bias = *(const float4*)(brel + o0);
    float4 acc[NPT];
    int n[NPT];
#pragma unroll
    for (int i = 0; i < NPT; ++i) {
        acc[i] = bias;
        n[i] = blockIdx.x * (SLOTS * NPT) + i * SLOTS + slot;
    }

#pragma unroll
    for (int k4 = 0; k4 < DIN / 4; ++k4) {
        float4 wr[4], wo[4];
#pragma unroll
        for (int u = 0; u < 4; ++u) {
            int k = 4 * k4 + u;
            wr[u] = *(const float4*)(Wrel + (size_t)k * DOUT + o0);
            wo[u] = *(const float4*)(Wroot + (size_t)k * DOUT + o0);
        }
#pragma unroll
        for (int i = 0; i < NPT; ++i) {
            int nn = (n[i] < N_NODES) ? n[i] : 0;
            float4 hv = ((const float4*)(h + (size_t)nn * DIN))[k4];
            float4 av = ((const float4*)(agg + (size_t)nn * DIN))[k4];
            const float* hp = (const float*)&hv;
            const float* ap = (const float*)&av;
#pragma unroll
            for (int u = 0; u < 4; ++u) {
                fma4(acc[i], ap[u], wr[u]);
                fma4(acc[i], hp[u], wo[u]);
            }
        }
    }
#pragma unroll
    for (int i = 0; i < NPT; ++i)
        if (n[i] < N_NODES)
            *(float4*)(out + (size_t)n[i] * DOUT + o0) = acc[i];
}

// ---------------------------------------------------------------------------
// P = h@Wrel ; Q = h@Wroot + brel  (same layout as gconv_v2)
template <int DIN, int DOUT>
__global__ __launch_bounds__(256) void prem_v2(
    const float* __restrict__ h, const float* __restrict__ Wrel,
    const float* __restrict__ brel, const float* __restrict__ Wroot,
    float* __restrict__ P, float* __restrict__ Q) {
    constexpr int OBL = (DOUT >= 64) ? 64 : 32;
    constexpr int LPN = OBL / 4;
    constexpr int SLOTS = 256 / LPN;
    constexpr int NPT = 4;
    const int q = threadIdx.x & (LPN - 1);
    const int slot = threadIdx.x / LPN;
    const int o0 = blockIdx.y * OBL + q * 4;

    float4 bias = *(const float4*)(brel + o0);
    float4 accp[NPT], accq[NPT];
    int n[NPT];
#pragma unroll
    for (int i = 0; i < NPT; ++i) {
        accp[i] = make_float4(0.f, 0.f, 0.f, 0.f);
        accq[i] = bias;
        n[i] = blockIdx.x * (SLOTS * NPT) + i * SLOTS + slot;
    }

#pragma unroll
    for (int k4 = 0; k4 < DIN / 4; ++k4) {
        float4 wr[4], wo[4];
#pragma unroll
        for (int u = 0; u < 4; ++u) {
            int k = 4 * k4 + u;
            wr[u] = *(const float4*)(Wrel + (size_t)k * DOUT + o0);
            wo[u] = *(const float4*)(Wroot + (size_t)k * DOUT + o0);
        }
#pragma unroll
        for (int i = 0; i < NPT; ++i) {
            int nn = (n[i] < N_NODES) ? n[i] : 0;
            float4 hv = ((const float4*)(h + (size_t)nn * DIN))[k4];
            const float* hp = (const float*)&hv;
#pragma unroll
            for (int u = 0; u < 4; ++u) {
                fma4(accp[i], hp[u], wr[u]);
                fma4(accq[i], hp[u], wo[u]);
            }
        }
    }
#pragma unroll
    for (int i = 0; i < NPT; ++i)
        if (n[i] < N_NODES) {
            *(float4*)(P + (size_t)n[i] * DOUT + o0) = accp[i];
            *(float4*)(Q + (size_t)n[i] * DOUT + o0) = accq[i];
        }
}

// ---------------------------------------------------------------------------
// agg[n][4q..4q+3] = sum over CSR row of h[ssrc[e]][4q..4q+3]
template <int LOGD>
__global__ __launch_bounds__(256) void gather_agg(
    const float* __restrict__ h, const int* __restrict__ rp,
    const int* __restrict__ ssrc, float4* __restrict__ agg) {
    constexpr int QSH = LOGD - 2;
    int tid = blockIdx.x * 256 + threadIdx.x;
    int node = tid >> QSH;
    if (node >= N_NODES) return;
    int q = tid & ((1 << QSH) - 1);
    int e0 = rp[node], e1 = rp[node + 1];
    float4 acc = make_float4(0.f, 0.f, 0.f, 0.f);
    for (int e = e0; e < e1; ++e) {
        const float4* row = (const float4*)(h + ((size_t)ssrc[e] << LOGD));
        float4 v = row[q];
        acc.x += v.x; acc.y += v.y; acc.z += v.z; acc.w += v.w;
    }
    agg[tid] = acc;
}

// out[n][f] = out_preloaded(Q) + sum over CSR row of P[ssrc[e]][f]
template <int LOGD>
__global__ __launch_bounds__(256) void gather_add(
    const float* __restrict__ P, const int* __restrict__ rp,
    const int* __restrict__ ssrc, float4* __restrict__ out) {
    constexpr int QSH = LOGD - 2;
    int tid = blockIdx.x * 256 + threadIdx.x;
    int node = tid >> QSH;
    if (node >= N_NODES) return;
    int q = tid & ((1 << QSH) - 1);
    int e0 = rp[node], e1 = rp[node + 1];
    float4 acc = out[tid];
    for (int e = e0; e < e1; ++e) {
        const float4* row = (const float4*)(P + ((size_t)ssrc[e] << LOGD));
        float4 v = row[q];
        acc.x += v.x; acc.y += v.y; acc.z += v.z; acc.w += v.w;
    }
    out[tid] = acc;
}

// ---------------------------------------------------------------------------
// fused: BN(layer3)+ReLU -> Linear(32,16)+ReLU -> Linear(16,2)
__global__ __launch_bounds__(256) void outmlp_kernel(
    const float* __restrict__ h, const float* __restrict__ stats,
    const float* __restrict__ g, const float* __restrict__ beta,
    const float* __restrict__ W1, const float* __restrict__ b1,
    const float* __restrict__ W2, const float* __restrict__ b2,
    float* __restrict__ out) {
    int n = blockIdx.x * 256 + threadIdx.x;
    if (n >= N_NODES) return;
    const float invN = 1.f / (float)N_NODES;
    const float4* hr4 = (const float4*)(h + (size_t)n * 32);
    float hv[32];
#pragma unroll
    for (int k4 = 0; k4 < 8; ++k4) {
        float4 v = hr4[k4];
        float* vp = (float*)&v;
#pragma unroll
        for (int c = 0; c < 4; ++c) {
            int f = 4 * k4 + c;
            float m = stats[f] * invN;
            float var = stats[32 + f] * invN - m * m;
            hv[f] = fmaxf((vp[c] - m) * rsqrtf(var + BN_EPS) * g[f] + beta[f], 0.f);
        }
    }
    float hid[16];
#pragma unroll
    for (int j = 0; j < 16; ++j) hid[j] = b1[j];
#pragma unroll
    for (int k = 0; k < 32; ++k) {
        float hk = hv[k];
#pragma unroll
        for (int j = 0; j < 16; ++j) hid[j] += hk * W1[k * 16 + j];
    }
    float o0 = b2[0], o1 = b2[1];
#pragma unroll
    for (int j = 0; j < 16; ++j) {
        float t = fmaxf(hid[j], 0.f);
        o0 += t * W2[j * 2 + 0];
        o1 += t * W2[j * 2 + 1];
    }
    out[n * 2 + 0] = o0;
    out[n * 2 + 1] = o1;
}

// ---------------------------------------------------------------------------
extern "C" void kernel_launch(void* const* d_in, const int* in_sizes, int n_in,
                              void* d_out, int out_size, void* d_ws, size_t ws_size,
                              hipStream_t stream) {
    const float* x        = (const float*)d_in[0];
    const int*   ei       = (const int*)d_in[1];
    const int*   src      = ei;
    const int*   dst      = ei + N_EDGES;
    const float* emb_W    = (const float*)d_in[2];
    const float* emb_b    = (const float*)d_in[3];
    const float* emb_g    = (const float*)d_in[4];
    const float* emb_beta = (const float*)d_in[5];
    const float* out_W1   = (const float*)d_in[26];
    const float* out_b1   = (const float*)d_in[27];
    const float* out_W2   = (const float*)d_in[28];
    const float* out_b2   = (const float*)d_in[29];

    float* ws = (float*)d_ws;
    const size_t HMAX = (size_t)N_NODES * 128;
    float* hA    = ws;
    float* hB    = ws + HMAX;
    float* P     = ws + 2 * HMAX;                        // N x 64 max
    float* stats = ws + 2 * HMAX + (size_t)N_NODES * 64; // 5 x 256
    int*   rp    = (int*)(stats + 5 * 256);
    int*   cnt   = rp + N_NODES + 1;
    int*   bsum  = cnt + N_NODES;
    int*   ssrc  = bsum + 256;

    float* st0 = stats;        // emb BN (D=32)
    float* st1 = stats + 256;  // L0 (D=64)
    float* st2 = stats + 512;  // L1 (D=128)
    float* st3 = stats + 768;  // L2 (D=64)
    float* st4 = stats + 1024; // L3 (D=32)

    const int BS = 256;
    const int NB = (N_NODES + BS - 1) / BS;  // 196

    // zero all stats once per call
    zero_f<<<2, BS, 0, stream>>>(stats, 5 * 256);

    // ---- CSR build ----
    zero_i<<<64, BS, 0, stream>>>(cnt, N_NODES);
    hist_kernel<<<1024, BS, 0, stream>>>(dst, cnt);
    scan1_kernel<<<NB, 256, 0, stream>>>(cnt, rp, bsum);
    scan2_kernel<<<1, 256, 0, stream>>>(bsum, NB);
    scan3_kernel<<<NB, 256, 0, stream>>>(rp, bsum);
    zero_i<<<64, BS, 0, stream>>>(cnt, N_NODES);
    fill_kernel<<<1024, BS, 0, stream>>>(src, dst, rp, cnt, ssrc);

    // ---- embedding + BN(32) ----
    emb_kernel<<<(N_NODES * 32 + BS - 1) / BS, BS, 0, stream>>>(x, emb_W, emb_b, hA);
    stats_kernel<<<512, BS, 2 * 32 * sizeof(float), stream>>>(hA, st0, 32);
    bn_kernel<<<1563, BS, 0, stream>>>((float4*)hA, emb_g, emb_beta, st0, 5, 0);

    // ---- layer 0: 32 -> 64 (gather input side) ----
    gather_agg<5><<<(N_NODES * 8 + BS - 1) / BS, BS, 0, stream>>>(hA, rp, ssrc, (float4*)P);
    gconv_v2<32, 64><<<dim3((N_NODES + 63) / 64, 1), BS, 0, stream>>>(
        hA, P, (const float*)d_in[6], (const float*)d_in[7], (const float*)d_in[8], hB);
    stats_kernel<<<512, BS, 2 * 64 * sizeof(float), stream>>>(hB, st1, 64);
    bn_kernel<<<3125, BS, 0, stream>>>((float4*)hB, (const float*)d_in[9], (const float*)d_in[10], st1, 6, 1);

    // ---- layer 1: 64 -> 128 (gather input side) ----
    gather_agg<6><<<(N_NODES * 16 + BS - 1) / BS, BS, 0, stream>>>(hB, rp, ssrc, (float4*)P);
    gconv_v2<64, 128><<<dim3((N_NODES + 63) / 64, 2), BS, 0, stream>>>(
        hB, P, (const float*)d_in[11], (const float*)d_in[12], (const float*)d_in[13], hA);
    stats_kernel<<<512, BS, 2 * 128 * sizeof(float), stream>>>(hA, st2, 128);
    bn_kernel<<<6250, BS, 0, stream>>>((float4*)hA, (const float*)d_in[14], (const float*)d_in[15], st2, 7, 1);

    // ---- layer 2: 128 -> 64 (pre-multiply then gather) ----
    prem_v2<128, 64><<<dim3((N_NODES + 63) / 64, 1), BS, 0, stream>>>(
        hA, (const float*)d_in[16], (const float*)d_in[17], (const float*)d_in[18], P, hB);
    gather_add<6><<<(N_NODES * 16 + BS - 1) / BS, BS, 0, stream>>>(P, rp, ssrc, (float4*)hB);
    stats_kernel<<<512, BS, 2 * 64 * sizeof(float), stream>>>(hB, st3, 64);
    bn_kernel<<<3125, BS, 0, stream>>>((float4*)hB, (const float*)d_in[19], (const float*)d_in[20], st3, 6, 1);

    // ---- layer 3: 64 -> 32 (pre-multiply then gather) ----
    prem_v2<64, 32><<<dim3((N_NODES + 127) / 128, 1), BS, 0, stream>>>(
        hB, (const float*)d_in[21], (const float*)d_in[22], (const float*)d_in[23], P, hA);
    gather_add<5><<<(N_NODES * 8 + BS - 1) / BS, BS, 0, stream>>>(P, rp, ssrc, (float4*)hA);
    stats_kernel<<<512, BS, 2 * 32 * sizeof(float), stream>>>(hA, st4, 32);

    // ---- fused BN(L3)+ReLU + output MLP ----
    outmlp_kernel<<<NB, BS, 0, stream>>>(
        hA, st4, (const float*)d_in[24], (const float*)d_in[25],
        out_W1, out_b1, out_W2, out_b2, (float*)d_out);
}

// Round 5
// 521.743 us; speedup vs baseline: 5.3431x; 5.2698x over previous
//
#include <hip/hip_runtime.h>

#define N_NODES 50000
#define N_EDGES 800000
#define BN_EPS 1e-5f

__device__ __forceinline__ void fma4(float4& a, float s, const float4& w) {
    a.x += s * w.x; a.y += s * w.y; a.z += s * w.z; a.w += s * w.w;
}

// ---------------------------------------------------------------------------
__global__ void zero_f(float* __restrict__ p, int n) {
    int i = blockIdx.x * blockDim.x + threadIdx.x;
    int stride = gridDim.x * blockDim.x;
    for (; i < n; i += stride) p[i] = 0.f;
}
__global__ void zero_i(int* __restrict__ p, int n) {
    int i = blockIdx.x * blockDim.x + threadIdx.x;
    int stride = gridDim.x * blockDim.x;
    for (; i < n; i += stride) p[i] = 0;
}

// ---------------------------------------------------------------------------
// CSR build
__global__ void hist_kernel(const int* __restrict__ dst, int* __restrict__ cnt) {
    int i = blockIdx.x * blockDim.x + threadIdx.x;
    int stride = gridDim.x * blockDim.x;
    for (; i < N_EDGES; i += stride) atomicAdd(&cnt[dst[i]], 1);
}
__global__ void scan1_kernel(const int* __restrict__ cnt, int* __restrict__ rp,
                             int* __restrict__ bsum) {
    __shared__ int s[256];
    int t = threadIdx.x;
    int idx = blockIdx.x * 256 + t;
    int v = (idx < N_NODES) ? cnt[idx] : 0;
    s[t] = v;
    __syncthreads();
    for (int off = 1; off < 256; off <<= 1) {
        int x = 0;
        if (t >= off) x = s[t - off];
        __syncthreads();
        s[t] += x;
        __syncthreads();
    }
    if (idx < N_NODES) rp[idx] = s[t] - v;
    if (t == 255) bsum[blockIdx.x] = s[255];
}
__global__ void scan2_kernel(int* __restrict__ bsum, int nb) {
    __shared__ int s[256];
    int t = threadIdx.x;
    int v = (t < nb) ? bsum[t] : 0;
    s[t] = v;
    __syncthreads();
    for (int off = 1; off < 256; off <<= 1) {
        int x = 0;
        if (t >= off) x = s[t - off];
        __syncthreads();
        s[t] += x;
        __syncthreads();
    }
    if (t < nb) bsum[t] = s[t] - v;
}
__global__ void scan3_kernel(int* __restrict__ rp, const int* __restrict__ bsum) {
    int idx = blockIdx.x * 256 + threadIdx.x;
    if (idx < N_NODES) rp[idx] += bsum[blockIdx.x];
    if (idx == 0) rp[N_NODES] = N_EDGES;
}
__global__ void fill_kernel(const int* __restrict__ src, const int* __restrict__ dst,
                            const int* __restrict__ rp, int* __restrict__ cur,
                            int* __restrict__ ssrc) {
    int i = blockIdx.x * blockDim.x + threadIdx.x;
    int stride = gridDim.x * blockDim.x;
    for (; i < N_EDGES; i += stride) {
        int d = dst[i];
        int p = rp[d] + atomicAdd(&cur[d], 1);
        ssrc[p] = src[i];
    }
}

// ---------------------------------------------------------------------------
// embedding Linear(5,32)+ReLU
__global__ void emb_kernel(const float* __restrict__ x, const float* __restrict__ W,
                           const float* __restrict__ b, float* __restrict__ out) {
    int idx = blockIdx.x * blockDim.x + threadIdx.x;
    if (idx >= N_NODES * 32) return;
    int n = idx >> 5;
    int o = idx & 31;
    const float* xr = x + n * 5;
    float acc = b[o];
#pragma unroll
    for (int k = 0; k < 5; ++k) acc += xr[k] * W[k * 32 + o];
    out[idx] = fmaxf(acc, 0.f);
}

// ---------------------------------------------------------------------------
// per-feature sum & sumsq (stats must be pre-zeroed)
__global__ void stats_kernel(const float* __restrict__ h, float* __restrict__ stats, int D) {
    extern __shared__ float lds[];  // 2*D floats
    int tid = threadIdx.x;
    for (int i = tid; i < 2 * D; i += blockDim.x) lds[i] = 0.f;
    __syncthreads();
    int gtid = blockIdx.x * blockDim.x + tid;
    int f = gtid & (D - 1);
    int row = gtid / D;
    int rstride = (gridDim.x * blockDim.x) / D;
    float s = 0.f, ss = 0.f;
    for (; row < N_NODES; row += rstride) {
        float v = h[row * D + f];
        s += v;
        ss += v * v;
    }
    atomicAdd(&lds[f], s);
    atomicAdd(&lds[D + f], ss);
    __syncthreads();
    for (int i = tid; i < 2 * D; i += blockDim.x) atomicAdd(&stats[i], lds[i]);
}

// in-place batchnorm (+ optional relu), float4
__global__ __launch_bounds__(256) void bn_kernel(
    float4* __restrict__ h, const float* __restrict__ g,
    const float* __restrict__ beta, const float* __restrict__ stats,
    int logD, int relu) {
    const int D = 1 << logD;
    const int total4 = N_NODES << (logD - 2);
    const float invN = 1.f / (float)N_NODES;
    int idx = blockIdx.x * blockDim.x + threadIdx.x;
    int stride = gridDim.x * blockDim.x;
    for (; idx < total4; idx += stride) {
        int f = (idx & ((D >> 2) - 1)) << 2;
        float4 v = h[idx];
        float* vp = (float*)&v;
#pragma unroll
        for (int c = 0; c < 4; ++c) {
            float m = stats[f + c] * invN;
            float var = stats[D + f + c] * invN - m * m;
            float y = (vp[c] - m) * rsqrtf(var + BN_EPS) * g[f + c] + beta[f + c];
            if (relu) y = fmaxf(y, 0.f);
            vp[c] = y;
        }
        h[idx] = v;
    }
}

// ---------------------------------------------------------------------------
// dual matmul, K-sliced register blocking (slice loop NOT unrolled -> bounded
// register pressure; within a slice: 16 weight float4 regs amortized over
// NPT=4 nodes -> ~8:1 FMA:VMEM).
// out[n][o] = brel[o] + agg[n]@Wrel[:,o] + h[n]@Wroot[:,o]
template <int DIN, int DOUT, int OBL>
__global__ __launch_bounds__(256) void gconv_v3(
    const float* __restrict__ h, const float* __restrict__ agg,
    const float* __restrict__ Wrel, const float* __restrict__ brel,
    const float* __restrict__ Wroot, float* __restrict__ out) {
    constexpr int LPN = OBL / 4;       // lanes per node
    constexpr int SLOTS = 256 / LPN;   // node slots per block
    constexpr int NPT = 4;             // nodes per thread
    constexpr int KS = 8;              // k-slice size
    const int q = threadIdx.x & (LPN - 1);
    const int slot = threadIdx.x / LPN;
    const int o0 = blockIdx.y * OBL + q * 4;
    const int nbase = blockIdx.x * (SLOTS * NPT) + slot;

    float4 bias = *(const float4*)(brel + o0);
    float4 acc[NPT];
#pragma unroll
    for (int i = 0; i < NPT; ++i) acc[i] = bias;

#pragma unroll 1
    for (int s = 0; s < DIN / KS; ++s) {
        const int k0 = s * KS;
        float4 wr[KS], wo[KS];
#pragma unroll
        for (int kk = 0; kk < KS; ++kk) {
            wr[kk] = *(const float4*)(Wrel + (size_t)(k0 + kk) * DOUT + o0);
            wo[kk] = *(const float4*)(Wroot + (size_t)(k0 + kk) * DOUT + o0);
        }
#pragma unroll
        for (int i = 0; i < NPT; ++i) {
            int n = nbase + i * SLOTS;
            int nn = (n < N_NODES) ? n : 0;
            const float4* hr = (const float4*)(h + (size_t)nn * DIN + k0);
            const float4* ar = (const float4*)(agg + (size_t)nn * DIN + k0);
            float4 hv[2] = {hr[0], hr[1]};
            float4 av[2] = {ar[0], ar[1]};
            const float* hp = (const float*)hv;
            const float* ap = (const float*)av;
#pragma unroll
            for (int kk = 0; kk < KS; ++kk) {
                fma4(acc[i], ap[kk], wr[kk]);
                fma4(acc[i], hp[kk], wo[kk]);
            }
        }
    }
#pragma unroll
    for (int i = 0; i < NPT; ++i) {
        int n = nbase + i * SLOTS;
        if (n < N_NODES) *(float4*)(out + (size_t)n * DOUT + o0) = acc[i];
    }
}

// ---------------------------------------------------------------------------
// P = h@Wrel ; Q = h@Wroot + brel   (same blocking as gconv_v3)
template <int DIN, int DOUT, int OBL>
__global__ __launch_bounds__(256) void prem_v3(
    const float* __restrict__ h, const float* __restrict__ Wrel,
    const float* __restrict__ brel, const float* __restrict__ Wroot,
    float* __restrict__ P, float* __restrict__ Q) {
    constexpr int LPN = OBL / 4;
    constexpr int SLOTS = 256 / LPN;
    constexpr int NPT = 4;
    constexpr int KS = 8;
    const int q = threadIdx.x & (LPN - 1);
    const int slot = threadIdx.x / LPN;
    const int o0 = blockIdx.y * OBL + q * 4;
    const int nbase = blockIdx.x * (SLOTS * NPT) + slot;

    float4 bias = *(const float4*)(brel + o0);
    float4 accp[NPT], accq[NPT];
#pragma unroll
    for (int i = 0; i < NPT; ++i) {
        accp[i] = make_float4(0.f, 0.f, 0.f, 0.f);
        accq[i] = bias;
    }

#pragma unroll 1
    for (int s = 0; s < DIN / KS; ++s) {
        const int k0 = s * KS;
        float4 wr[KS], wo[KS];
#pragma unroll
        for (int kk = 0; kk < KS; ++kk) {
            wr[kk] = *(const float4*)(Wrel + (size_t)(k0 + kk) * DOUT + o0);
            wo[kk] = *(const float4*)(Wroot + (size_t)(k0 + kk) * DOUT + o0);
        }
#pragma unroll
        for (int i = 0; i < NPT; ++i) {
            int n = nbase + i * SLOTS;
            int nn = (n < N_NODES) ? n : 0;
            const float4* hr = (const float4*)(h + (size_t)nn * DIN + k0);
            float4 hv[2] = {hr[0], hr[1]};
            const float* hp = (const float*)hv;
#pragma unroll
            for (int kk = 0; kk < KS; ++kk) {
                fma4(accp[i], hp[kk], wr[kk]);
                fma4(accq[i], hp[kk], wo[kk]);
            }
        }
    }
#pragma unroll
    for (int i = 0; i < NPT; ++i) {
        int n = nbase + i * SLOTS;
        if (n < N_NODES) {
            *(float4*)(P + (size_t)n * DOUT + o0) = accp[i];
            *(float4*)(Q + (size_t)n * DOUT + o0) = accq[i];
        }
    }
}

// ---------------------------------------------------------------------------
// agg[n][4q..4q+3] = sum over CSR row of h[ssrc[e]][4q..4q+3]
template <int LOGD>
__global__ __launch_bounds__(256) void gather_agg(
    const float* __restrict__ h, const int* __restrict__ rp,
    const int* __restrict__ ssrc, float4* __restrict__ agg) {
    constexpr int QSH = LOGD - 2;
    int tid = blockIdx.x * 256 + threadIdx.x;
    int node = tid >> QSH;
    if (node >= N_NODES) return;
    int q = tid & ((1 << QSH) - 1);
    int e0 = rp[node], e1 = rp[node + 1];
    float4 acc = make_float4(0.f, 0.f, 0.f, 0.f);
    for (int e = e0; e < e1; ++e) {
        const float4* row = (const float4*)(h + ((size_t)ssrc[e] << LOGD));
        float4 v = row[q];
        acc.x += v.x; acc.y += v.y; acc.z += v.z; acc.w += v.w;
    }
    agg[tid] = acc;
}

// out[n][f] = out_preloaded(Q) + sum over CSR row of P[ssrc[e]][f]
template <int LOGD>
__global__ __launch_bounds__(256) void gather_add(
    const float* __restrict__ P, const int* __restrict__ rp,
    const int* __restrict__ ssrc, float4* __restrict__ out) {
    constexpr int QSH = LOGD - 2;
    int tid = blockIdx.x * 256 + threadIdx.x;
    int node = tid >> QSH;
    if (node >= N_NODES) return;
    int q = tid & ((1 << QSH) - 1);
    int e0 = rp[node], e1 = rp[node + 1];
    float4 acc = out[tid];
    for (int e = e0; e < e1; ++e) {
        const float4* row = (const float4*)(P + ((size_t)ssrc[e] << LOGD));
        float4 v = row[q];
        acc.x += v.x; acc.y += v.y; acc.z += v.z; acc.w += v.w;
    }
    out[tid] = acc;
}

// ---------------------------------------------------------------------------
// fused: BN(layer3)+ReLU -> Linear(32,16)+ReLU -> Linear(16,2)
__global__ __launch_bounds__(256) void outmlp_kernel(
    const float* __restrict__ h, const float* __restrict__ stats,
    const float* __restrict__ g, const float* __restrict__ beta,
    const float* __restrict__ W1, const float* __restrict__ b1,
    const float* __restrict__ W2, const float* __restrict__ b2,
    float* __restrict__ out) {
    int n = blockIdx.x * 256 + threadIdx.x;
    if (n >= N_NODES) return;
    const float invN = 1.f / (float)N_NODES;
    const float4* hr4 = (const float4*)(h + (size_t)n * 32);
    float hv[32];
#pragma unroll
    for (int k4 = 0; k4 < 8; ++k4) {
        float4 v = hr4[k4];
        float* vp = (float*)&v;
#pragma unroll
        for (int c = 0; c < 4; ++c) {
            int f = 4 * k4 + c;
            float m = stats[f] * invN;
            float var = stats[32 + f] * invN - m * m;
            hv[f] = fmaxf((vp[c] - m) * rsqrtf(var + BN_EPS) * g[f] + beta[f], 0.f);
        }
    }
    float hid[16];
#pragma unroll
    for (int j = 0; j < 16; ++j) hid[j] = b1[j];
#pragma unroll
    for (int k = 0; k < 32; ++k) {
        float hk = hv[k];
#pragma unroll
        for (int j = 0; j < 16; ++j) hid[j] += hk * W1[k * 16 + j];
    }
    float o0 = b2[0], o1 = b2[1];
#pragma unroll
    for (int j = 0; j < 16; ++j) {
        float t = fmaxf(hid[j], 0.f);
        o0 += t * W2[j * 2 + 0];
        o1 += t * W2[j * 2 + 1];
    }
    out[n * 2 + 0] = o0;
    out[n * 2 + 1] = o1;
}

// ---------------------------------------------------------------------------
extern "C" void kernel_launch(void* const* d_in, const int* in_sizes, int n_in,
                              void* d_out, int out_size, void* d_ws, size_t ws_size,
                              hipStream_t stream) {
    const float* x        = (const float*)d_in[0];
    const int*   ei       = (const int*)d_in[1];
    const int*   src      = ei;
    const int*   dst      = ei + N_EDGES;
    const float* emb_W    = (const float*)d_in[2];
    const float* emb_b    = (const float*)d_in[3];
    const float* emb_g    = (const float*)d_in[4];
    const float* emb_beta = (const float*)d_in[5];
    const float* out_W1   = (const float*)d_in[26];
    const float* out_b1   = (const float*)d_in[27];
    const float* out_W2   = (const float*)d_in[28];
    const float* out_b2   = (const float*)d_in[29];

    float* ws = (float*)d_ws;
    const size_t HMAX = (size_t)N_NODES * 128;
    float* hA    = ws;
    float* hB    = ws + HMAX;
    float* P     = ws + 2 * HMAX;                        // N x 64 max
    float* stats = ws + 2 * HMAX + (size_t)N_NODES * 64; // 5 x 256
    int*   rp    = (int*)(stats + 5 * 256);
    int*   cnt   = rp + N_NODES + 1;
    int*   bsum  = cnt + N_NODES;
    int*   ssrc  = bsum + 256;

    float* st0 = stats;        // emb BN (D=32)
    float* st1 = stats + 256;  // L0 (D=64)
    float* st2 = stats + 512;  // L1 (D=128)
    float* st3 = stats + 768;  // L2 (D=64)
    float* st4 = stats + 1024; // L3 (D=32)

    const int BS = 256;
    const int NB = (N_NODES + BS - 1) / BS;  // 196

    // zero all stats once per call
    zero_f<<<2, BS, 0, stream>>>(stats, 5 * 256);

    // ---- CSR build ----
    zero_i<<<64, BS, 0, stream>>>(cnt, N_NODES);
    hist_kernel<<<1024, BS, 0, stream>>>(dst, cnt);
    scan1_kernel<<<NB, 256, 0, stream>>>(cnt, rp, bsum);
    scan2_kernel<<<1, 256, 0, stream>>>(bsum, NB);
    scan3_kernel<<<NB, 256, 0, stream>>>(rp, bsum);
    zero_i<<<64, BS, 0, stream>>>(cnt, N_NODES);
    fill_kernel<<<1024, BS, 0, stream>>>(src, dst, rp, cnt, ssrc);

    // ---- embedding + BN(32) ----
    emb_kernel<<<(N_NODES * 32 + BS - 1) / BS, BS, 0, stream>>>(x, emb_W, emb_b, hA);
    stats_kernel<<<512, BS, 2 * 32 * sizeof(float), stream>>>(hA, st0, 32);
    bn_kernel<<<1563, BS, 0, stream>>>((float4*)hA, emb_g, emb_beta, st0, 5, 0);

    // ---- layer 0: 32 -> 64 (gather input side) ----
    gather_agg<5><<<(N_NODES * 8 + BS - 1) / BS, BS, 0, stream>>>(hA, rp, ssrc, (float4*)P);
    gconv_v3<32, 64, 64><<<dim3((N_NODES + 63) / 64, 1), BS, 0, stream>>>(
        hA, P, (const float*)d_in[6], (const float*)d_in[7], (const float*)d_in[8], hB);
    stats_kernel<<<512, BS, 2 * 64 * sizeof(float), stream>>>(hB, st1, 64);
    bn_kernel<<<3125, BS, 0, stream>>>((float4*)hB, (const float*)d_in[9], (const float*)d_in[10], st1, 6, 1);

    // ---- layer 1: 64 -> 128 (gather input side) ----
    gather_agg<6><<<(N_NODES * 16 + BS - 1) / BS, BS, 0, stream>>>(hB, rp, ssrc, (float4*)P);
    gconv_v3<64, 128, 64><<<dim3((N_NODES + 63) / 64, 2), BS, 0, stream>>>(
        hB, P, (const float*)d_in[11], (const float*)d_in[12], (const float*)d_in[13], hA);
    stats_kernel<<<512, BS, 2 * 128 * sizeof(float), stream>>>(hA, st2, 128);
    bn_kernel<<<6250, BS, 0, stream>>>((float4*)hA, (const float*)d_in[14], (const float*)d_in[15], st2, 7, 1);

    // ---- layer 2: 128 -> 64 (pre-multiply then gather) ----
    prem_v3<128, 64, 64><<<dim3((N_NODES + 63) / 64, 1), BS, 0, stream>>>(
        hA, (const float*)d_in[16], (const float*)d_in[17], (const float*)d_in[18], P, hB);
    gather_add<6><<<(N_NODES * 16 + BS - 1) / BS, BS, 0, stream>>>(P, rp, ssrc, (float4*)hB);
    stats_kernel<<<512, BS, 2 * 64 * sizeof(float), stream>>>(hB, st3, 64);
    bn_kernel<<<3125, BS, 0, stream>>>((float4*)hB, (const float*)d_in[19], (const float*)d_in[20], st3, 6, 1);

    // ---- layer 3: 64 -> 32 (pre-multiply then gather) ----
    prem_v3<64, 32, 32><<<dim3((N_NODES + 127) / 128, 1), BS, 0, stream>>>(
        hB, (const float*)d_in[21], (const float*)d_in[22], (const float*)d_in[23], P, hA);
    gather_add<5><<<(N_NODES * 8 + BS - 1) / BS, BS, 0, stream>>>(P, rp, ssrc, (float4*)hA);
    stats_kernel<<<512, BS, 2 * 32 * sizeof(float), stream>>>(hA, st4, 32);

    // ---- fused BN(L3)+ReLU + output MLP ----
    outmlp_kernel<<<NB, BS, 0, stream>>>(
        hA, st4, (const float*)d_in[24], (const float*)d_in[25],
        out_W1, out_b1, out_W2, out_b2, (float*)d_out);
}